// Round 6
// baseline (378.423 us; speedup 1.0000x reference)
//
#include <hip/hip_runtime.h>

#define NV 30000
#define MP 32

typedef short s16x8 __attribute__((ext_vector_type(8)));
typedef float f32x4 __attribute__((ext_vector_type(4)));

// f32 -> bf16 (RNE) bit helpers (init-time splits)
__device__ __forceinline__ unsigned short bf16h(float f) {
    unsigned int u = __float_as_uint(f);
    return (unsigned short)((u + 0x7FFFu + ((u >> 16) & 1u)) >> 16);
}
__device__ __forceinline__ float bf16f(unsigned short h) {
    return __uint_as_float(((unsigned int)h) << 16);
}
// packed f32x2 -> bf16x2 (gfx950)
__device__ __forceinline__ unsigned int cvtpk(float a, float b) {
    unsigned int r;
    asm("v_cvt_pk_bf16_f32 %0, %1, %2" : "=v"(r) : "v"(a), "v"(b));
    return r;
}
// in-wave LDS RAW fence (rule #18: sched_barrier after inline lgkmcnt)
__device__ __forceinline__ void lgkm0sb() {
    asm volatile("s_waitcnt lgkmcnt(0)" ::: "memory");
    __builtin_amdgcn_sched_barrier(0);
}

// ---------------------------------------------------------------------------
// GEMM1: wave-per-voxel, voxstats fused (shuffle reductions), h1 via MFMA
// (bf16 3-pass). No block barriers in the main loop. Writes vstat, vmax1,
// vmin1 (raw h1 extrema) and global BN1 sum/sumsq (f64 atomics, block-reduced).
// ---------------------------------------------------------------------------
#define G1BLK 512
#define G1IT  15   // 512*4*15 = 30720 >= NV
__global__ __launch_bounds__(256) void k_gemm1(
    const float* __restrict__ feats, const int* __restrict__ npts,
    const int* __restrict__ coors, const float* __restrict__ W1,
    float* __restrict__ vstat,
    float* __restrict__ vmax1, float* __restrict__ vmin1,
    double* __restrict__ sum1, double* __restrict__ sumsq1)
{
    __shared__ unsigned short x1h[4][32*16];   // per-wave [32 rows][16 k]
    __shared__ unsigned short x1l[4][32*16];
    __shared__ float reds[4][64], redq[4][64];

    const int t = threadIdx.x, wave = t>>6, lane = t&63;
    const int lr = lane&15, g = lane>>4, m = lane&31;

    // W1 raw A-frags: A[ch][k], ch = ct*16+lr, k = g*8+j (k>=13 -> 0)
    s16x8 Wh[4], Wl[4];
    #pragma unroll
    for (int ct=0; ct<4; ++ct)
        #pragma unroll
        for (int j=0;j<8;++j) {
            int k = g*8 + j;
            float v = (k < 13) ? W1[k*64 + ct*16 + lr] : 0.f;
            unsigned short h = bf16h(v);
            Wh[ct][j] = (short)h; Wl[ct][j] = (short)bf16h(v - bf16f(h));
        }
    float accs[4][4], accq[4][4];
    #pragma unroll
    for (int ct=0;ct<4;++ct)
        #pragma unroll
        for (int r=0;r<4;++r) { accs[ct][r]=0.f; accq[ct][r]=0.f; }

    for (int it=0; it<G1IT; ++it) {
        const int v = (it*G1BLK + blockIdx.x)*4 + wave;
        const bool act = v < NV;
        if (act && lane < 32) {
            const int np = npts[v];
            const float fnp = (float)np;
            const float4 p = ((const float4*)feats)[(size_t)v*MP + m];
            const float msk = (m < np) ? 1.0f : 0.0f;
            // fused voxstats: butterfly over 32 point-lanes
            float ux=p.x, uy=p.y, uz=p.z;
            float wx=p.x*msk, wy=p.y*msk, wz=p.z*msk;
            #pragma unroll
            for (int off=1; off<32; off<<=1) {
                ux += __shfl_xor(ux,off); uy += __shfl_xor(uy,off); uz += __shfl_xor(uz,off);
                wx += __shfl_xor(wx,off); wy += __shfl_xor(wy,off); wz += __shfl_xor(wz,off);
            }
            const float pmx=ux/fnp, pmy=uy/fnp, pmz=uz/fnp;
            const float vmx=wx/fnp, vmy=wy/fnp, vmz=wz/fnp;
            const float ddx=p.x-vmx, ddy=p.y-vmy, ddz=p.z-vmz;
            float d = sqrtf(ddx*ddx+ddy*ddy+ddz*ddz)*msk;
            #pragma unroll
            for (int off=1; off<32; off<<=1) d += __shfl_xor(d,off);
            const float md = d/fnp, dens = fnp/0.16f;
            if (m == 0) {
                float* o = vstat + (size_t)v*8;
                *(float4*)o       = make_float4(pmx,pmy,pmz,vmx);
                *(float4*)(o + 4) = make_float4(vmy,vmz,md,dens);
            }
            const float cx = (float)coors[v*4+3]*0.2f + 0.1f;
            const float cy = (float)coors[v*4+2]*0.2f - 39.9f;
            const float cz = (float)coors[v*4+1]*4.0f - 1.0f;
            float xv[16];
            xv[0]=p.x*msk; xv[1]=p.y*msk; xv[2]=p.z*msk; xv[3]=p.w*msk;
            xv[4]=(p.x-pmx)*msk; xv[5]=(p.y-pmy)*msk; xv[6]=(p.z-pmz)*msk;
            xv[7]=(p.x-cx)*msk; xv[8]=(p.y-cy)*msk; xv[9]=(p.z-cz)*msk;
            xv[10]=sqrtf(p.x*p.x+p.y*p.y+p.z*p.z)*msk;
            xv[11]=dens*msk; xv[12]=md*msk; xv[13]=0.f; xv[14]=0.f; xv[15]=0.f;
            unsigned int hu[8], lu[8];
            #pragma unroll
            for (int j=0;j<8;++j) {
                unsigned int hw = cvtpk(xv[2*j], xv[2*j+1]);
                float f0 = __uint_as_float(hw << 16);
                float f1 = __uint_as_float(hw & 0xffff0000u);
                lu[j] = cvtpk(xv[2*j]-f0, xv[2*j+1]-f1);
                hu[j] = hw;
            }
            const int base = m*16, sw = (m&7)<<3;
            *(uint4*)&x1h[wave][(base  ) ^ sw] = make_uint4(hu[0],hu[1],hu[2],hu[3]);
            *(uint4*)&x1h[wave][(base+8) ^ sw] = make_uint4(hu[4],hu[5],hu[6],hu[7]);
            *(uint4*)&x1l[wave][(base  ) ^ sw] = make_uint4(lu[0],lu[1],lu[2],lu[3]);
            *(uint4*)&x1l[wave][(base+8) ^ sw] = make_uint4(lu[4],lu[5],lu[6],lu[7]);
        }
        lgkm0sb();   // wave-private x1 RAW
        if (act) {
            const s16x8 zz = {0,0,0,0,0,0,0,0};
            s16x8 Bh[2], Bl[2];
            #pragma unroll
            for (int rg=0; rg<2; ++rg) {
                const int row = rg*16 + lr;
                if (g < 2) {
                    const int e = (row*16 + g*8) ^ ((row&7)<<3);
                    Bh[rg] = *(const s16x8*)&x1h[wave][e];
                    Bl[rg] = *(const s16x8*)&x1l[wave][e];
                } else { Bh[rg] = zz; Bl[rg] = zz; }
            }
            #pragma unroll
            for (int ct=0; ct<4; ++ct) {
                f32x4 h0; h0[0]=0.f;h0[1]=0.f;h0[2]=0.f;h0[3]=0.f;
                f32x4 h1v = h0;
                h0 = __builtin_amdgcn_mfma_f32_16x16x32_bf16(Wh[ct], Bh[0], h0, 0,0,0);
                h0 = __builtin_amdgcn_mfma_f32_16x16x32_bf16(Wl[ct], Bh[0], h0, 0,0,0);
                h0 = __builtin_amdgcn_mfma_f32_16x16x32_bf16(Wh[ct], Bl[0], h0, 0,0,0);
                h1v = __builtin_amdgcn_mfma_f32_16x16x32_bf16(Wh[ct], Bh[1], h1v, 0,0,0);
                h1v = __builtin_amdgcn_mfma_f32_16x16x32_bf16(Wl[ct], Bh[1], h1v, 0,0,0);
                h1v = __builtin_amdgcn_mfma_f32_16x16x32_bf16(Wh[ct], Bl[1], h1v, 0,0,0);
                // lane holds ch = ct*16+g*4+r, points rg*16+lr
                float mxv[4], mnv[4];
                #pragma unroll
                for (int r=0;r<4;++r) {
                    float mx = fmaxf(h0[r], h1v[r]), mn = fminf(h0[r], h1v[r]);
                    float s  = h0[r] + h1v[r];
                    float q  = fmaf(h0[r],h0[r], h1v[r]*h1v[r]);
                    #pragma unroll
                    for (int off=1; off<16; off<<=1) {
                        mx = fmaxf(mx, __shfl_xor(mx,off));
                        mn = fminf(mn, __shfl_xor(mn,off));
                        s += __shfl_xor(s,off);
                        q += __shfl_xor(q,off);
                    }
                    accs[ct][r] += s; accq[ct][r] += q;
                    mxv[r]=mx; mnv[r]=mn;
                }
                if (lr == 0) {
                    *(float4*)&vmax1[(size_t)v*64 + ct*16 + g*4] = make_float4(mxv[0],mxv[1],mxv[2],mxv[3]);
                    *(float4*)&vmin1[(size_t)v*64 + ct*16 + g*4] = make_float4(mnv[0],mnv[1],mnv[2],mnv[3]);
                }
            }
        }
    }
    if (lr == 0) {
        #pragma unroll
        for (int ct=0;ct<4;++ct) {
            *(float4*)&reds[wave][ct*16+g*4] = make_float4(accs[ct][0],accs[ct][1],accs[ct][2],accs[ct][3]);
            *(float4*)&redq[wave][ct*16+g*4] = make_float4(accq[ct][0],accq[ct][1],accq[ct][2],accq[ct][3]);
        }
    }
    __syncthreads();
    if (t < 64) {
        float s = reds[0][t]+reds[1][t]+reds[2][t]+reds[3][t];
        float q = redq[0][t]+redq[1][t]+redq[2][t]+redq[3][t];
        atomicAdd(&sum1[t], (double)s);
        atomicAdd(&sumsq1[t], (double)q);
    }
}

__global__ void k_fin1(const double* __restrict__ sum1, const double* __restrict__ sumsq1,
                       const float* __restrict__ g1, const float* __restrict__ b1,
                       float* __restrict__ sc1, float* __restrict__ sh1) {
    int c = threadIdx.x;
    if (c >= 64) return;
    double cnt = (double)NV * MP;
    double mu = sum1[c]/cnt;
    double var = sumsq1[c]/cnt - mu*mu;
    double rs = 1.0 / sqrt(var + 1e-3);
    double sc = (double)g1[c]*rs;
    sc1[c] = (float)sc;
    sh1[c] = (float)((double)b1[c] - mu*sc);
}

// t[v][c] = agg[v][0:64] @ W2[64:128][c]
__global__ __launch_bounds__(256) void k_aggt(
    const float* __restrict__ vmax1, const float* __restrict__ vmin1,
    const float* __restrict__ sc1, const float* __restrict__ sh1,
    const float* __restrict__ W2, float* __restrict__ tbuf)
{
    __shared__ float w2T[128][68];
    __shared__ float aggls[2][64];
    const int t = threadIdx.x;
    for (int i = t; i < 128*64; i += 256) {
        int k = i >> 7, c = i & 127;
        w2T[c][k] = W2[(64+k)*128 + c];
    }
    __syncthreads();
    const int v2 = t >> 7, c = t & 127;
    const int iters = (NV/2 + 511) / 512;   // 30
    for (int it=0; it<iters; ++it) {
        int pair = it*512 + blockIdx.x;
        bool act = pair < NV/2;
        if (act && t < 128) {
            int vv = t >> 6, k = t & 63;
            float s = sc1[k];
            size_t o = (size_t)(pair*2+vv)*64 + k;
            float v = (s >= 0.f) ? vmax1[o] : vmin1[o];
            aggls[vv][k] = fmaxf(fmaf(v, s, sh1[k]), 0.f);
        }
        __syncthreads();
        if (act) {
            float acc = 0.f;
            #pragma unroll
            for (int k4=0; k4<64; k4+=4) {
                float4 a = *(const float4*)&aggls[v2][k4];
                float4 wv = *(const float4*)&w2T[c][k4];
                acc = fmaf(a.x,wv.x,acc); acc = fmaf(a.y,wv.y,acc);
                acc = fmaf(a.z,wv.z,acc); acc = fmaf(a.w,wv.w,acc);
            }
            tbuf[(size_t)(pair*2+v2)*128 + c] = acc;
        }
        __syncthreads();
    }
}

// ---------------------------------------------------------------------------
// GEMM2: 128-thr blocks (2 waves), tile = 2 voxels x 128 ch, K=64.
// Double-buffered x1/x2 -> 2 cheap 2-wave barriers/iter. Wave w: h1 for
// ct-pair {2w,2w+1} (MFMA, sc-folded W1), then N-slice w*64..+64 of GEMM2.
// ---------------------------------------------------------------------------
#define G2BLK 1024
#define G2IT  15   // 1024*15 = 15360 >= NV/2
__global__ __launch_bounds__(128) void k_gemm2(
    const float* __restrict__ feats, const int* __restrict__ npts,
    const int* __restrict__ coors, const float* __restrict__ vstat,
    const float* __restrict__ W1, const float* __restrict__ W2,
    const float* __restrict__ sc1, const float* __restrict__ sh1,
    const float* __restrict__ tbuf,
    float* __restrict__ vmax2, float* __restrict__ vmin2,
    double* __restrict__ sum2, double* __restrict__ sumsq2)
{
    __shared__ unsigned short x1h[2][64*16], x1l[2][64*16];  // 8 KB
    __shared__ unsigned short x2h[2][64*64], x2l[2][64*64];  // 32 KB

    const int t = threadIdx.x, w = t>>6, lane = t&63;
    const int lr = lane&15, g = lane>>4, m = lane&31;

    // W2a B-frags (wave's 64-col slice): nt 0..3, ks 0..1, hi/lo
    s16x8 B2h[4][2], B2l[4][2];
    {
        const int col0 = w*64 + lr;
        #pragma unroll
        for (int nt=0; nt<4; ++nt)
            #pragma unroll
            for (int ks=0; ks<2; ++ks)
                #pragma unroll
                for (int j=0; j<8; ++j) {
                    float v = W2[(ks*32 + g*8 + j)*128 + col0 + nt*16];
                    unsigned short h = bf16h(v);
                    B2h[nt][ks][j] = (short)h;
                    B2l[nt][ks][j] = (short)bf16h(v - bf16f(h));
                }
    }
    // W1' A-frags (sc1 folded), wave's ct-pair
    s16x8 W1h[2], W1l[2];
    float shr[2][4];
    #pragma unroll
    for (int cc=0; cc<2; ++cc) {
        const int ct = w*2 + cc;
        const int ch = ct*16 + lr;
        const float scv = sc1[ch];
        #pragma unroll
        for (int j=0; j<8; ++j) {
            int k = g*8 + j;
            float v = (k < 13) ? W1[k*64 + ch]*scv : 0.f;
            unsigned short h = bf16h(v);
            W1h[cc][j] = (short)h;
            W1l[cc][j] = (short)bf16h(v - bf16f(h));
        }
        #pragma unroll
        for (int r=0; r<4; ++r) shr[cc][r] = sh1[ct*16 + g*4 + r];
    }
    double dsum[4] = {0.0,0.0,0.0,0.0}, dsq[4] = {0.0,0.0,0.0,0.0};

    for (int it=0; it<G2IT; ++it) {
        const int pair = it*G2BLK + blockIdx.x;
        const bool act = pair < NV/2;
        const int vox0 = pair*2;
        const int cur = it & 1;
        float tvv[2][4];
        if (act) {
            #pragma unroll
            for (int v=0; v<2; ++v)
                #pragma unroll
                for (int nt=0; nt<4; ++nt)
                    tvv[v][nt] = tbuf[(size_t)(vox0+v)*128 + w*64 + nt*16 + lr];
            if (lane < 32) {
                const int vox = vox0 + w;
                const int row = w*32 + m;
                const int np = npts[vox];
                const float cx = (float)coors[vox*4+3]*0.2f + 0.1f;
                const float cy = (float)coors[vox*4+2]*0.2f - 39.9f;
                const float cz = (float)coors[vox*4+1]*4.0f - 1.0f;
                const float4 vsa = *(const float4*)&vstat[(size_t)vox*8];
                const float4 vsb = *(const float4*)&vstat[(size_t)vox*8+4];
                const float4 p = ((const float4*)feats)[(size_t)vox*MP + m];
                const float msk = (m < np) ? 1.0f : 0.0f;
                float xv[16];
                xv[0]=p.x*msk; xv[1]=p.y*msk; xv[2]=p.z*msk; xv[3]=p.w*msk;
                xv[4]=(p.x-vsa.x)*msk; xv[5]=(p.y-vsa.y)*msk; xv[6]=(p.z-vsa.z)*msk;
                xv[7]=(p.x-cx)*msk; xv[8]=(p.y-cy)*msk; xv[9]=(p.z-cz)*msk;
                xv[10]=sqrtf(p.x*p.x+p.y*p.y+p.z*p.z)*msk;
                xv[11]=vsb.w*msk; xv[12]=vsb.z*msk; xv[13]=0.f; xv[14]=0.f; xv[15]=0.f;
                unsigned int hu[8], lu[8];
                #pragma unroll
                for (int j=0;j<8;++j) {
                    unsigned int hw = cvtpk(xv[2*j], xv[2*j+1]);
                    float f0 = __uint_as_float(hw << 16);
                    float f1 = __uint_as_float(hw & 0xffff0000u);
                    lu[j] = cvtpk(xv[2*j]-f0, xv[2*j+1]-f1);
                    hu[j] = hw;
                }
                const int base = row*16, sw = (row&7)<<3;
                *(uint4*)&x1h[cur][(base  ) ^ sw] = make_uint4(hu[0],hu[1],hu[2],hu[3]);
                *(uint4*)&x1h[cur][(base+8) ^ sw] = make_uint4(hu[4],hu[5],hu[6],hu[7]);
                *(uint4*)&x1l[cur][(base  ) ^ sw] = make_uint4(lu[0],lu[1],lu[2],lu[3]);
                *(uint4*)&x1l[cur][(base+8) ^ sw] = make_uint4(lu[4],lu[5],lu[6],lu[7]);
            }
        }
        __syncthreads();
        if (act) {
            const s16x8 zz = {0,0,0,0,0,0,0,0};
            s16x8 Xh[4], Xl[4];
            #pragma unroll
            for (int rg=0; rg<4; ++rg) {
                const int row = rg*16 + lr;
                if (g < 2) {
                    const int e = (row*16 + g*8) ^ ((row&7)<<3);
                    Xh[rg] = *(const s16x8*)&x1h[cur][e];
                    Xl[rg] = *(const s16x8*)&x1l[cur][e];
                } else { Xh[rg] = zz; Xl[rg] = zz; }
            }
            #pragma unroll
            for (int cc=0; cc<2; ++cc) {
                const int ct = w*2 + cc;
                #pragma unroll
                for (int rg=0; rg<4; ++rg) {
                    f32x4 hv;
                    hv[0]=shr[cc][0]; hv[1]=shr[cc][1]; hv[2]=shr[cc][2]; hv[3]=shr[cc][3];
                    hv = __builtin_amdgcn_mfma_f32_16x16x32_bf16(W1h[cc], Xh[rg], hv, 0,0,0);
                    hv = __builtin_amdgcn_mfma_f32_16x16x32_bf16(W1l[cc], Xh[rg], hv, 0,0,0);
                    hv = __builtin_amdgcn_mfma_f32_16x16x32_bf16(W1h[cc], Xl[rg], hv, 0,0,0);
                    float a0 = fmaxf(hv[0],0.f), a1 = fmaxf(hv[1],0.f);
                    float a2 = fmaxf(hv[2],0.f), a3 = fmaxf(hv[3],0.f);
                    unsigned int h01 = cvtpk(a0,a1), h23 = cvtpk(a2,a3);
                    float r0 = a0 - __uint_as_float(h01<<16);
                    float r1 = a1 - __uint_as_float(h01 & 0xffff0000u);
                    float r2 = a2 - __uint_as_float(h23<<16);
                    float r3 = a3 - __uint_as_float(h23 & 0xffff0000u);
                    unsigned int l01 = cvtpk(r0,r1), l23 = cvtpk(r2,r3);
                    const int p = rg*16 + lr;
                    const int e = (p*64 + ct*16 + g*4) ^ ((p&7)<<3);
                    *(uint2*)&x2h[cur][e] = make_uint2(h01,h23);
                    *(uint2*)&x2l[cur][e] = make_uint2(l01,l23);
                }
            }
        }
        __syncthreads();
        if (act) {
            f32x4 acc[4][4];
            #pragma unroll
            for (int mt=0;mt<4;++mt)
                #pragma unroll
                for (int nt=0;nt<4;++nt) {
                    acc[mt][nt][0]=0.f; acc[mt][nt][1]=0.f;
                    acc[mt][nt][2]=0.f; acc[mt][nt][3]=0.f;
                }
            #pragma unroll
            for (int ks=0; ks<2; ++ks) {
                s16x8 Ah[4], Al[4];
                #pragma unroll
                for (int mt=0;mt<4;++mt) {
                    const int p = mt*16 + lr;
                    const int e = (p*64 + ks*32 + g*8) ^ ((p&7)<<3);
                    Ah[mt] = *(const s16x8*)&x2h[cur][e];
                    Al[mt] = *(const s16x8*)&x2l[cur][e];
                }
                #pragma unroll
                for (int mt=0;mt<4;++mt)
                    #pragma unroll
                    for (int nt=0;nt<4;++nt) {
                        acc[mt][nt] = __builtin_amdgcn_mfma_f32_16x16x32_bf16(Ah[mt], B2h[nt][ks], acc[mt][nt], 0,0,0);
                        acc[mt][nt] = __builtin_amdgcn_mfma_f32_16x16x32_bf16(Al[mt], B2h[nt][ks], acc[mt][nt], 0,0,0);
                        acc[mt][nt] = __builtin_amdgcn_mfma_f32_16x16x32_bf16(Ah[mt], B2l[nt][ks], acc[mt][nt], 0,0,0);
                    }
            }
            // epilogue: lane holds ch = w*64+nt*16+lr, points mt*16+g*4+r
            #pragma unroll
            for (int nt=0; nt<4; ++nt) {
                float sl = 0.f, ql = 0.f;
                #pragma unroll
                for (int v=0; v<2; ++v) {
                    const float tv = tvv[v][nt];
                    float mx = -3.402823466e38f, mn = 3.402823466e38f;
                    #pragma unroll
                    for (int mh=0; mh<2; ++mh) {
                        const f32x4 q4 = acc[v*2+mh][nt];
                        #pragma unroll
                        for (int r=0;r<4;++r) {
                            mx = fmaxf(mx, q4[r]); mn = fminf(mn, q4[r]);
                            const float e = q4[r] + tv;
                            sl += e; ql = fmaf(e,e,ql);
                        }
                    }
                    mx = fmaxf(mx, __shfl_xor(mx,16)); mn = fminf(mn, __shfl_xor(mn,16));
                    mx = fmaxf(mx, __shfl_xor(mx,32)); mn = fminf(mn, __shfl_xor(mn,32));
                    if (lane < 16) {
                        const size_t o = (size_t)(vox0+v)*128 + w*64 + nt*16 + lr;
                        vmax2[o] = mx + tv; vmin2[o] = mn + tv;
                    }
                }
                dsum[nt] += (double)sl; dsq[nt] += (double)ql;
            }
        }
    }
    #pragma unroll
    for (int nt=0; nt<4; ++nt) {
        double s = dsum[nt], q = dsq[nt];
        s += __shfl_xor(s,16); q += __shfl_xor(q,16);
        s += __shfl_xor(s,32); q += __shfl_xor(q,32);
        if (lane < 16) {
            atomicAdd(&sum2[w*64 + nt*16 + lr], s);
            atomicAdd(&sumsq2[w*64 + nt*16 + lr], q);
        }
    }
}

__global__ void k_fin2(const double* __restrict__ sum2, const double* __restrict__ sumsq2,
                       const float* __restrict__ g2, const float* __restrict__ b2,
                       float* __restrict__ sc2, float* __restrict__ sh2) {
    int c = threadIdx.x;
    if (c >= 128) return;
    double cnt = (double)NV * MP;
    double mu = sum2[c]/cnt;
    double var = sumsq2[c]/cnt - mu*mu;
    double rs = 1.0 / sqrt(var + 1e-3);
    double sc = (double)g2[c]*rs;
    sc2[c] = (float)sc;
    sh2[c] = (float)((double)b2[c] - mu*sc);
}

__global__ void k_out(const float* __restrict__ vmax2, const float* __restrict__ vmin2,
                      const float* __restrict__ sc2, const float* __restrict__ sh2,
                      float* __restrict__ out) {
    int t = blockIdx.x*blockDim.x + threadIdx.x;
    if (t >= NV*128) return;
    int c = t & 127;
    float s = sc2[c];
    float v = (s >= 0.f) ? vmax2[t] : vmin2[t];
    out[t] = fmaxf(fmaf(v, s, sh2[c]), 0.f);
}

extern "C" void kernel_launch(void* const* d_in, const int* in_sizes, int n_in,
                              void* d_out, int out_size, void* d_ws, size_t ws_size,
                              hipStream_t stream) {
    const float* feats = (const float*)d_in[0];
    const int*   npts  = (const int*)d_in[1];
    const int*   coors = (const int*)d_in[2];
    const float* W1    = (const float*)d_in[3];
    const float* g1    = (const float*)d_in[4];
    const float* b1    = (const float*)d_in[5];
    const float* W2    = (const float*)d_in[6];
    const float* g2    = (const float*)d_in[7];
    const float* b2    = (const float*)d_in[8];
    float* out = (float*)d_out;

    double* sum1   = (double*)d_ws;            // 64
    double* sumsq1 = sum1 + 64;                // 64
    double* sum2   = sumsq1 + 64;              // 128
    double* sumsq2 = sum2 + 128;               // 128 (384 doubles)
    float* fb = (float*)(sumsq2 + 128);
    float* vstat = fb;            fb += (size_t)NV*8;
    float* vmax1 = fb;            fb += (size_t)NV*64;
    float* vmin1 = fb;            fb += (size_t)NV*64;
    float* vmax2 = fb;            fb += (size_t)NV*128;
    float* vmin2 = fb;            fb += (size_t)NV*128;
    float* tbuf  = fb;            fb += (size_t)NV*128;
    float* sc1 = fb;              fb += 64;
    float* sh1 = fb;              fb += 64;
    float* sc2 = fb;              fb += 128;
    float* sh2 = fb;              fb += 128;

    hipMemsetAsync(d_ws, 0, 384*sizeof(double), stream);
    hipLaunchKernelGGL(k_gemm1, dim3(G1BLK), dim3(256), 0, stream,
                       feats, npts, coors, W1, vstat, vmax1, vmin1, sum1, sumsq1);
    hipLaunchKernelGGL(k_fin1, dim3(1), dim3(64), 0, stream,
                       sum1, sumsq1, g1, b1, sc1, sh1);
    hipLaunchKernelGGL(k_aggt, dim3(512), dim3(256), 0, stream,
                       vmax1, vmin1, sc1, sh1, W2, tbuf);
    hipLaunchKernelGGL(k_gemm2, dim3(G2BLK), dim3(128), 0, stream,
                       feats, npts, coors, vstat, W1, W2, sc1, sh1, tbuf,
                       vmax2, vmin2, sum2, sumsq2);
    hipLaunchKernelGGL(k_fin2, dim3(1), dim3(128), 0, stream,
                       sum2, sumsq2, g2, b2, sc2, sh2);
    hipLaunchKernelGGL(k_out, dim3(NV*128/256), dim3(256), 0, stream,
                       vmax2, vmin2, sc2, sh2, out);
}